// Round 17
// baseline (135.504 us; speedup 1.0000x reference)
//
#include <hip/hip_runtime.h>
#include <hip/hip_bf16.h>
#include <cstdint>

#define TSEQ 2048
#define DMODEL 2048
#define NHEAD 32
#define NKV 8
#define DHEAD 64
#define QKVN 3072
#define AON 2048

using bf16x8 = __attribute__((ext_vector_type(8))) short;
using bf16x4 = __attribute__((ext_vector_type(4))) short;
using f32x4  = __attribute__((ext_vector_type(4))) float;

__device__ __forceinline__ ushort f2bf(float f) {
  union { float f; uint32_t u; } v; v.f = f;
  uint32_t u = v.u;
  return (ushort)((u + 0x7fffu + ((u >> 16) & 1u)) >> 16);
}

__device__ __forceinline__ float bf2f(ushort u) {
  union { uint32_t u; float f; } v; v.u = ((uint32_t)u) << 16;
  return v.f;
}

__device__ __forceinline__ float fexp2(float x) {
#if __has_builtin(__builtin_amdgcn_exp2f)
  return __builtin_amdgcn_exp2f(x);
#else
  return __expf(x * 0.69314718055994531f);
#endif
}

__device__ __forceinline__ uint32_t cvtpk(float lo, float hi) {
  uint32_t r;
  asm("v_cvt_pk_bf16_f32 %0, %1, %2" : "=v"(r) : "v"(lo), "v"(hi));
  return r;
}

__device__ __forceinline__ void gload16(const void* g, void* l) {
  __builtin_amdgcn_global_load_lds((const __attribute__((address_space(1))) void*)g,
                                   (__attribute__((address_space(3))) void*)l,
                                   16, 0, 0);
}

// ---------------- fused f32 -> bf16 conversion (X, Wq, Wk, Wv) ----------------
#define RG0 1048576   // X        (2048*2048/4)
#define RG1 2097152   // + Wq     (2048*2048/4)
#define RG2 2359296   // + Wk     ( 512*2048/4)
#define RG3 2621440   // + Wv     ( 512*2048/4)
__global__ void k_cvt_all(const float* __restrict__ X, const float* __restrict__ Wq,
                          const float* __restrict__ Wk, const float* __restrict__ Wv,
                          ushort* __restrict__ Xb, ushort* __restrict__ Wqkvb) {
  int gid = blockIdx.x * blockDim.x + threadIdx.x;
  int stride = gridDim.x * blockDim.x;
  for (int i = gid; i < RG3; i += stride) {
    const float4* s; ushort4* d;
    if (i < RG0)      { s = (const float4*)X  + i;         d = (ushort4*)Xb + i; }
    else if (i < RG1) { s = (const float4*)Wq + (i - RG0); d = (ushort4*)Wqkvb + (i - RG0); }
    else if (i < RG2) { s = (const float4*)Wk + (i - RG1); d = (ushort4*)Wqkvb + 1048576 + (i - RG1); }
    else              { s = (const float4*)Wv + (i - RG2); d = (ushort4*)Wqkvb + 1310720 + (i - RG2); }
    float4 v = *s;
    ushort4 o;
    o.x = f2bf(v.x); o.y = f2bf(v.y); o.z = f2bf(v.z); o.w = f2bf(v.w);
    *d = o;
  }
}

// ---------------- QKV GEMM, split-K=2 (8 waves, 128x128 tile, 3 LDS buffers / depth-2) ----------------
// grid (24,16,2): z selects K-half and partial buffer. 768 blocks = exactly 3/CU co-resident.
__global__ __launch_bounds__(512) void k_gemm_qkv_split(
    const ushort* __restrict__ A, const ushort* __restrict__ B,
    ushort* __restrict__ P0, ushort* __restrict__ P1,
    int M, int N, int K)
{
  __shared__ ushort As[3][128 * 32];
  __shared__ ushort Bs[3][128 * 32];
  const int m0 = blockIdx.y * 128, n0 = blockIdx.x * 128;
  const int kzbase = blockIdx.z * (K >> 1);
  ushort* Pz = blockIdx.z ? P1 : P0;
  const int tid = threadIdx.x;
  const int w = tid >> 6, lane = tid & 63, lg = lane >> 4, lr = lane & 15;
  const int wr = (w >> 1) * 32, wc = (w & 1) * 64;

  f32x4 acc[2][4];
#pragma unroll
  for (int i = 0; i < 2; ++i)
#pragma unroll
    for (int j = 0; j < 4; ++j) acc[i][j] = (f32x4){0.f, 0.f, 0.f, 0.f};

  const int nt = K >> 6;   // (K/2)/32 = 32 K-steps per half

  auto stage = [&](int b, int t) {
    const int k0 = kzbase + (t << 5);
    {
      int ci = tid;
      int row = ci >> 2, c = ci & 3;
      int clog = c ^ ((row >> 1) & 3);
      gload16(A + (size_t)(m0 + row) * K + k0 + clog * 8, As[b] + ci * 8);
    }
    {
      int ci = tid;
      int row = ci >> 2, c = ci & 3;
      int clog = c ^ ((row >> 1) & 3);
      gload16(B + (size_t)(n0 + row) * K + k0 + clog * 8, Bs[b] + ci * 8);
    }
  };

  stage(0, 0); stage(1, 1);

  int b0 = 0;
  for (int t = 0; t < nt; ++t) {
    if (nt - t >= 2) asm volatile("s_waitcnt vmcnt(2)" ::: "memory");
    else             asm volatile("s_waitcnt vmcnt(0)" ::: "memory");
    __builtin_amdgcn_s_barrier();
    __builtin_amdgcn_sched_barrier(0);

    const ushort* as = As[b0];
    const ushort* bs = Bs[b0];
    bf16x8 af[2], bfr[4];
#pragma unroll
    for (int i = 0; i < 2; ++i) {
      int ra = wr + i * 16 + lr;
      af[i] = *reinterpret_cast<const bf16x8*>(as + ra * 32 + ((lg ^ ((ra >> 1) & 3)) << 3));
    }
#pragma unroll
    for (int j = 0; j < 4; ++j) {
      int rb = wc + j * 16 + lr;
      bfr[j] = *reinterpret_cast<const bf16x8*>(bs + rb * 32 + ((lg ^ ((rb >> 1) & 3)) << 3));
    }
    asm volatile("s_waitcnt lgkmcnt(0)" ::: "memory");
    __builtin_amdgcn_sched_barrier(0);

    if (t + 2 < nt) {
      int b2 = b0 + 2; if (b2 >= 3) b2 -= 3;
      stage(b2, t + 2);
    }

#pragma unroll
    for (int i = 0; i < 2; ++i)
#pragma unroll
      for (int j = 0; j < 4; ++j)
        acc[i][j] = __builtin_amdgcn_mfma_f32_16x16x32_bf16(af[i], bfr[j], acc[i][j], 0, 0, 0);

    b0 = (b0 + 1 == 3) ? 0 : b0 + 1;
  }

#pragma unroll
  for (int i = 0; i < 2; ++i)
#pragma unroll
    for (int j = 0; j < 4; ++j)
#pragma unroll
      for (int r = 0; r < 4; ++r) {
        size_t idx = (size_t)(m0 + wr + i * 16 + lg * 4 + r) * N + n0 + wc + j * 16 + lr;
        Pz[idx] = f2bf(acc[i][j][r]);
      }
}

// ---------------- RMSNorm + RoPE + layout epilogue (R6-proven normrope, reads P0+P1) ----------------
// Q is scaled by 0.125 * log2(e) so attention can use pure exp2 softmax.
__global__ __launch_bounds__(256) void k_qkv_epi(
    const ushort* __restrict__ P0, const ushort* __restrict__ P1,
    const int* __restrict__ pos,
    const float* __restrict__ qw, const float* __restrict__ kw,
    ushort* __restrict__ Qb, ushort* __restrict__ Kb, ushort* __restrict__ Vt)
{
  int gw = blockIdx.x * 4 + (threadIdx.x >> 6);
  int lane = threadIdx.x & 63;
  int t = gw / 48, u = gw % 48;
  if (t >= TSEQ) return;
  if (u < 40) {
    int col = (u < 32) ? u * 64 + lane : 2048 + (u - 32) * 64 + lane;
    size_t idx = (size_t)t * QKVN + col;
    float x = bf2f(P0[idx]) + bf2f(P1[idx]);
    float ss = x * x;
#pragma unroll
    for (int mm = 32; mm; mm >>= 1) ss += __shfl_xor(ss, mm);
    float r = rsqrtf(ss * (1.0f / 64.0f) + 1e-6f);
    x = x * r * ((u < 32) ? qw[lane] : kw[lane]);
    int p = (u < 32) ? pos[t] : t;
    int j = lane >> 1;
    float invf = fexp2((float)j * (-0.41524101186092029f));
    float s, c;
    __sincosf((float)p * invf, &s, &c);
    float other = __shfl_xor(x, 1);
    float out = (lane & 1) ? (other * s + x * c) : (x * c - other * s);
    if (u < 32)
      Qb[((size_t)u * TSEQ + t) * 64 + lane] = f2bf(out * 0.18033688011112043f);
    else
      Kb[((size_t)(u - 32) * TSEQ + t) * 64 + lane] = f2bf(out);
  } else {
    int hv = u - 40;
    size_t idx = (size_t)t * QKVN + 2560 + hv * 64 + lane;
    float x = bf2f(P0[idx]) + bf2f(P1[idx]);
    Vt[((size_t)hv * 64 + lane) * TSEQ + t] = f2bf(x);
  }
}

// ---------------- bf16 GEMM: 64x128 tile, 4 LDS buffers / depth-3 (AO, frozen) ----------------
__global__ __launch_bounds__(256) void k_gemm64(
    const ushort* __restrict__ A, const ushort* __restrict__ B,
    float* __restrict__ C, int M, int N, int K)
{
  __shared__ ushort As[4][64 * 32];
  __shared__ ushort Bs[4][128 * 32];
  const int m0 = blockIdx.y * 64, n0 = blockIdx.x * 128;
  const int tid = threadIdx.x;
  const int w = tid >> 6, lane = tid & 63, lg = lane >> 4, lr = lane & 15;
  const int wr = (w >> 1) * 32, wc = (w & 1) * 64;

  f32x4 acc[2][4];
#pragma unroll
  for (int i = 0; i < 2; ++i)
#pragma unroll
    for (int j = 0; j < 4; ++j) acc[i][j] = (f32x4){0.f, 0.f, 0.f, 0.f};

  const int nt = K >> 5;

  auto stage = [&](int b, int t) {
    const int k0 = t << 5;
    {
      int ci = tid;
      int row = ci >> 2, c = ci & 3;
      int clog = c ^ ((row >> 1) & 3);
      gload16(A + (size_t)(m0 + row) * K + k0 + clog * 8, As[b] + ci * 8);
    }
#pragma unroll
    for (int j = 0; j < 2; ++j) {
      int ci = j * 256 + tid;
      int row = ci >> 2, c = ci & 3;
      int clog = c ^ ((row >> 1) & 3);
      gload16(B + (size_t)(n0 + row) * K + k0 + clog * 8, Bs[b] + ci * 8);
    }
  };

  stage(0, 0); stage(1, 1); stage(2, 2);

  for (int t = 0; t < nt; ++t) {
    int rem = nt - t;
    if (rem >= 3)      asm volatile("s_waitcnt vmcnt(6)" ::: "memory");
    else if (rem == 2) asm volatile("s_waitcnt vmcnt(3)" ::: "memory");
    else               asm volatile("s_waitcnt vmcnt(0)" ::: "memory");
    __builtin_amdgcn_s_barrier();
    __builtin_amdgcn_sched_barrier(0);

    const ushort* as = As[t & 3];
    const ushort* bs = Bs[t & 3];
    bf16x8 af[2], bfr[4];
#pragma unroll
    for (int i = 0; i < 2; ++i) {
      int ra = wr + i * 16 + lr;
      af[i] = *reinterpret_cast<const bf16x8*>(as + ra * 32 + ((lg ^ ((ra >> 1) & 3)) << 3));
    }
#pragma unroll
    for (int j = 0; j < 4; ++j) {
      int rb = wc + j * 16 + lr;
      bfr[j] = *reinterpret_cast<const bf16x8*>(bs + rb * 32 + ((lg ^ ((rb >> 1) & 3)) << 3));
    }
    asm volatile("s_waitcnt lgkmcnt(0)" ::: "memory");
    __builtin_amdgcn_sched_barrier(0);

    if (t + 3 < nt) stage((t + 3) & 3, t + 3);

#pragma unroll
    for (int i = 0; i < 2; ++i)
#pragma unroll
      for (int j = 0; j < 4; ++j)
        acc[i][j] = __builtin_amdgcn_mfma_f32_16x16x32_bf16(af[i], bfr[j], acc[i][j], 0, 0, 0);
  }

#pragma unroll
  for (int i = 0; i < 2; ++i)
#pragma unroll
    for (int j = 0; j < 4; ++j)
#pragma unroll
      for (int r = 0; r < 4; ++r)
        C[(size_t)(m0 + wr + i * 16 + lg * 4 + r) * N + n0 + wc + j * 16 + lr] = acc[i][j][r];
}

// ---------------- flash attention (frozen R16: 128-q block, 8 waves, KVBLK=64, LPT, +Wo cvt tail) ----------------
__global__ __launch_bounds__(512) void k_attn(
    const ushort* __restrict__ Qb, const ushort* __restrict__ Kb,
    const ushort* __restrict__ Vt, ushort* __restrict__ AO,
    const float* __restrict__ Wo, ushort* __restrict__ Wob)
{
  __shared__ ushort Ks[2][64 * 64];
  __shared__ ushort Vs[2][64 * 64];

  const int h = blockIdx.x;
  const int q0 = ((int)gridDim.y - 1 - (int)blockIdx.y) * 128;
  const int tid = threadIdx.x;
  const int w = tid >> 6, lane = tid & 63;
  const int lg = lane >> 4, lr = lane & 15;
  const int qrow = q0 + w * 16 + lr;

  const ushort* qp = Qb + ((size_t)h * TSEQ + qrow) * 64;
  const bf16x8 qf0 = *reinterpret_cast<const bf16x8*>(qp + lg * 8);
  const bf16x8 qf1 = *reinterpret_cast<const bf16x8*>(qp + 32 + lg * 8);
  const int hk = h >> 2;
  const char* Kh = (const char*)(Kb + (size_t)hk * TSEQ * 64);
  const char* Vh = (const char*)(Vt + (size_t)hk * 64 * TSEQ);

  float m = -1e30f, lsum = 0.0f;
  f32x4 o[4];
#pragma unroll
  for (int dt = 0; dt < 4; ++dt) o[dt] = (f32x4){0.f, 0.f, 0.f, 0.f};

  const int wlo = (q0 >= 1152) ? (q0 - 1024) : 128;
  int nwin = (q0 + 64 - wlo) / 64 + 1;
  if (nwin < 0) nwin = 0;
  const int ntiles = 2 + nwin;
  const int qw0 = q0 + w * 16;
  const int wmaxstart = ((qw0 + 15 - 1023) > 128) ? (qw0 + 15 - 1023) : 128;
  const int wminstart = ((qw0 - 1023) > 128) ? (qw0 - 1023) : 128;
  const int wstart_lane = ((qrow - 1023) > 128) ? (qrow - 1023) : 128;

  auto stage = [&](int b, int kb) {
    int off = tid * 16;
    int r = off >> 7, bp = off & 127;
    int bs = bp ^ ((r & 7) << 4);
    gload16(Kh + (size_t)(kb + r) * 128 + bs, (char*)Ks[b] + off);
    gload16(Vh + (size_t)r * (TSEQ * 2) + (size_t)kb * 2 + bs, (char*)Vs[b] + off);
  };

  stage(0, 0);

  for (int ti = 0; ti < ntiles; ++ti) {
    const int kb = (ti < 2) ? ti * 64 : wlo + (ti - 2) * 64;
    __syncthreads();
    if (ti + 1 < ntiles) {
      const int kb1 = (ti + 1 < 2) ? (ti + 1) * 64 : wlo + (ti - 1) * 64;
      stage((ti + 1) & 1, kb1);
    }
    if (ti >= 2 && ((kb > qw0 + 15) || (kb + 63 < wminstart))) continue;

    const char* ks = (const char*)Ks[ti & 1];
    const char* vs = (const char*)Vs[ti & 1];
    const bool needmask = (ti >= 2) && !((kb + 63 <= qw0) && (kb >= wmaxstart));

    f32x4 st[4];
#pragma unroll
    for (int s = 0; s < 4; ++s) {
      int row = s * 16 + lr;
      int sw = (row & 7) << 4;
      bf16x8 kf0 = *reinterpret_cast<const bf16x8*>(ks + row * 128 + ((lg * 16) ^ sw));
      bf16x8 kf1 = *reinterpret_cast<const bf16x8*>(ks + row * 128 + ((64 + lg * 16) ^ sw));
      f32x4 acc = (f32x4){0.f, 0.f, 0.f, 0.f};
      acc = __builtin_amdgcn_mfma_f32_16x16x32_bf16(kf0, qf0, acc, 0, 0, 0);
      acc = __builtin_amdgcn_mfma_f32_16x16x32_bf16(kf1, qf1, acc, 0, 0, 0);
      st[s] = acc;
    }
    if (needmask) {
#pragma unroll
      for (int s = 0; s < 4; ++s)
#pragma unroll
        for (int r = 0; r < 4; ++r) {
          int key = kb + s * 16 + lg * 4 + r;
          bool ok = (key >= wstart_lane) && (key <= qrow);
          if (!ok) st[s][r] = -1e30f;
        }
    }
    float pmax = st[0][0];
#pragma unroll
    for (int s = 0; s < 4; ++s)
#pragma unroll
      for (int r = 0; r < 4; ++r) pmax = fmaxf(pmax, st[s][r]);
    pmax = fmaxf(pmax, __shfl_xor(pmax, 16));
    pmax = fmaxf(pmax, __shfl_xor(pmax, 32));

    const bool defer = __all(pmax <= m + 8.0f);
    if (!defer) {
      float mnew = fmaxf(m, pmax);
      float sc = fexp2(m - mnew);
      m = mnew;
      lsum *= sc;
#pragma unroll
      for (int dt = 0; dt < 4; ++dt) o[dt] = o[dt] * sc;
    }

    float psum = 0.f;
    bf16x4 pb[4];
#pragma unroll
    for (int s = 0; s < 4; ++s) {
      float e0 = fexp2(st[s][0] - m);
      float e1 = fexp2(st[s][1] - m);
      float e2 = fexp2(st[s][2] - m);
      float e3 = fexp2(st[s][3] - m);
      psum += (e0 + e1) + (e2 + e3);
      union { uint32_t u[2]; bf16x4 b; } pk;
      pk.u[0] = cvtpk(e0, e1);
      pk.u[1] = cvtpk(e2, e3);
      pb[s] = pk.b;
    }
    psum += __shfl_xor(psum, 16);
    psum += __shfl_xor(psum, 32);
    lsum += psum;

#pragma unroll
    for (int dt = 0; dt < 4; ++dt) {
      int row = dt * 16 + lr;
      int sw = (row & 7) << 4;
#pragma unroll
      for (int s = 0; s < 4; ++s) {
        bf16x4 vf = *reinterpret_cast<const bf16x4*>(vs + row * 128 + ((s * 32 + lg * 8) ^ sw));
        o[dt] = __builtin_amdgcn_mfma_f32_16x16x16bf16_1k(vf, pb[s], o[dt], 0, 0, 0);
      }
    }
  }

  float inv = 1.0f / lsum;
#pragma unroll
  for (int dt = 0; dt < 4; ++dt)
#pragma unroll
    for (int r = 0; r < 4; ++r)
      AO[(size_t)qrow * AON + h * 64 + dt * 16 + lg * 4 + r] = f2bf(o[dt][r] * inv);

  // -------- absorbed Wo f32->bf16 conversion (hides in the LPT idle tail) --------
  {
    int bid = blockIdx.y * gridDim.x + blockIdx.x;
    int idx = bid * 512 + tid;
#pragma unroll
    for (int it = 0; it < 4; ++it) {
      int i = idx + it * 262144;
      float4 v = reinterpret_cast<const float4*>(Wo)[i];
      ushort4 ov;
      ov.x = f2bf(v.x); ov.y = f2bf(v.y); ov.z = f2bf(v.z); ov.w = f2bf(v.w);
      reinterpret_cast<ushort4*>(Wob)[i] = ov;
    }
  }
}

// ---------------- launch ----------------
extern "C" void kernel_launch(void* const* d_in, const int* in_sizes, int n_in,
                              void* d_out, int out_size, void* d_ws, size_t ws_size,
                              hipStream_t stream) {
  const float* hs = (const float*)d_in[0];
  const int* pos  = (const int*)d_in[1];
  const float* Wq = (const float*)d_in[2];
  const float* Wk = (const float*)d_in[3];
  const float* Wv = (const float*)d_in[4];
  const float* Wo = (const float*)d_in[5];
  const float* qw = (const float*)d_in[6];
  const float* kw = (const float*)d_in[7];
  float* out = (float*)d_out;

  char* ws = (char*)d_ws;
  ushort* Xb    = (ushort*)ws; ws += (size_t)2048 * 2048 * 2;     // 8 MB
  ushort* Wqkvb = (ushort*)ws; ws += (size_t)3072 * 2048 * 2;     // 12 MB
  ushort* Qb    = (ushort*)ws; ws += (size_t)32 * 2048 * 64 * 2;  // 8 MB
  ushort* Kb    = (ushort*)ws; ws += (size_t)8 * 2048 * 64 * 2;   // 2 MB
  ushort* Vt    = (ushort*)ws; ws += (size_t)8 * 64 * 2048 * 2;   // 2 MB
  // region below: P0/P1 live gemm->epi; Wob/AO live attn->gemm64 (aliased, non-overlapping lifetimes)
  char* region = ws;
  ushort* P0  = (ushort*)region;                                   // 12 MB
  ushort* P1  = (ushort*)(region + (size_t)2048 * 3072 * 2);       // 12 MB
  ushort* Wob = (ushort*)region;                                   // 8 MB (after epi done)
  ushort* AO  = (ushort*)(region + (size_t)2048 * 2048 * 2);       // 8 MB

  k_cvt_all<<<2048, 256, 0, stream>>>(hs, Wq, Wk, Wv, Xb, Wqkvb);

  k_gemm_qkv_split<<<dim3(QKVN / 128, TSEQ / 128, 2), 512, 0, stream>>>(
      Xb, Wqkvb, P0, P1, TSEQ, QKVN, DMODEL);
  k_qkv_epi<<<(TSEQ * 48) / 4, 256, 0, stream>>>(P0, P1, pos, qw, kw, Qb, Kb, Vt);
  k_attn<<<dim3(NHEAD, TSEQ / 128), 512, 0, stream>>>(Qb, Kb, Vt, AO, Wo, Wob);
  k_gemm64<<<dim3(DMODEL / 128, TSEQ / 64), 256, 0, stream>>>(AO, Wob, out, TSEQ, DMODEL, AON);
}

// Round 18
// 119.848 us; speedup vs baseline: 1.1306x; 1.1306x over previous
//
#include <hip/hip_runtime.h>
#include <hip/hip_bf16.h>
#include <cstdint>

#define TSEQ 2048
#define DMODEL 2048
#define NHEAD 32
#define NKV 8
#define DHEAD 64
#define QKVN 3072
#define AON 2048

using bf16x8 = __attribute__((ext_vector_type(8))) short;
using bf16x4 = __attribute__((ext_vector_type(4))) short;
using f32x4  = __attribute__((ext_vector_type(4))) float;

__device__ __forceinline__ ushort f2bf(float f) {
  union { float f; uint32_t u; } v; v.f = f;
  uint32_t u = v.u;
  return (ushort)((u + 0x7fffu + ((u >> 16) & 1u)) >> 16);
}

__device__ __forceinline__ float fexp2(float x) {
#if __has_builtin(__builtin_amdgcn_exp2f)
  return __builtin_amdgcn_exp2f(x);
#else
  return __expf(x * 0.69314718055994531f);
#endif
}

__device__ __forceinline__ uint32_t cvtpk(float lo, float hi) {
  uint32_t r;
  asm("v_cvt_pk_bf16_f32 %0, %1, %2" : "=v"(r) : "v"(lo), "v"(hi));
  return r;
}

__device__ __forceinline__ void gload16(const void* g, void* l) {
  __builtin_amdgcn_global_load_lds((const __attribute__((address_space(1))) void*)g,
                                   (__attribute__((address_space(3))) void*)l,
                                   16, 0, 0);
}

// ---------------- fused f32 -> bf16 conversion (X, Wq, Wk, Wv) + RoPE sincos table ----------------
// Wo conversion is ABSORBED into k_attn's idle tail (it's only needed by the AO GEMM).
#define RG0 1048576   // X        (2048*2048/4)
#define RG1 2097152   // + Wq     (2048*2048/4)
#define RG2 2359296   // + Wk     ( 512*2048/4)
#define RG3 2621440   // + Wv     ( 512*2048/4)
__global__ void k_cvt_all(const float* __restrict__ X, const float* __restrict__ Wq,
                          const float* __restrict__ Wk, const float* __restrict__ Wv,
                          const int* __restrict__ pos,
                          ushort* __restrict__ Xb, ushort* __restrict__ Wqkvb,
                          float4* __restrict__ Tbl) {
  int gid = blockIdx.x * blockDim.x + threadIdx.x;
  if (gid < TSEQ * 32) {
    int t = gid >> 5, jj = gid & 31;
    float invf = fexp2((float)jj * (-0.41524101186092029f));
    float qs, qc, ks, kc;
    __sincosf((float)pos[t] * invf, &qs, &qc);
    __sincosf((float)t * invf, &ks, &kc);
    Tbl[gid] = make_float4(qc * 0.18033688011112043f, qs * 0.18033688011112043f, kc, ks);
  }
  int stride = gridDim.x * blockDim.x;
  for (int i = gid; i < RG3; i += stride) {
    const float4* s; ushort4* d;
    if (i < RG0)      { s = (const float4*)X  + i;         d = (ushort4*)Xb + i; }
    else if (i < RG1) { s = (const float4*)Wq + (i - RG0); d = (ushort4*)Wqkvb + (i - RG0); }
    else if (i < RG2) { s = (const float4*)Wk + (i - RG1); d = (ushort4*)Wqkvb + 1048576 + (i - RG1); }
    else              { s = (const float4*)Wv + (i - RG2); d = (ushort4*)Wqkvb + 1310720 + (i - RG2); }
    float4 v = *s;
    ushort4 o;
    o.x = f2bf(v.x); o.y = f2bf(v.y); o.z = f2bf(v.z); o.w = f2bf(v.w);
    *d = o;
  }
}

// ---------------- QKV GEMM (8 waves, 128x128 tile, 4 LDS buffers / depth-3) ----------------
// + fused RMSNorm/RoPE/layout epilogue (R13-proven best config).
__global__ __launch_bounds__(512) void k_gemm_qkv(
    const ushort* __restrict__ A, const ushort* __restrict__ B,
    const float* __restrict__ qw, const float* __restrict__ kw,
    const float4* __restrict__ Tbl,
    ushort* __restrict__ Qb, ushort* __restrict__ Kb, ushort* __restrict__ Vt,
    int M, int N, int K)
{
  __shared__ ushort As[4][128 * 32];
  __shared__ ushort Bs[4][128 * 32];
  const int m0 = blockIdx.y * 128, n0 = blockIdx.x * 128;
  const int tid = threadIdx.x;
  const int w = tid >> 6, lane = tid & 63, lg = lane >> 4, lr = lane & 15;
  const int wr = (w >> 1) * 32, wc = (w & 1) * 64;

  f32x4 acc[2][4];
#pragma unroll
  for (int i = 0; i < 2; ++i)
#pragma unroll
    for (int j = 0; j < 4; ++j) acc[i][j] = (f32x4){0.f, 0.f, 0.f, 0.f};

  const int nt = K >> 5;

  auto stage = [&](int b, int t) {
    const int k0 = t << 5;
    {
      int ci = tid;
      int row = ci >> 2, c = ci & 3;
      int clog = c ^ ((row >> 1) & 3);
      gload16(A + (size_t)(m0 + row) * K + k0 + clog * 8, As[b] + ci * 8);
    }
    {
      int ci = tid;
      int row = ci >> 2, c = ci & 3;
      int clog = c ^ ((row >> 1) & 3);
      gload16(B + (size_t)(n0 + row) * K + k0 + clog * 8, Bs[b] + ci * 8);
    }
  };

  stage(0, 0); stage(1, 1); stage(2, 2);

  for (int t = 0; t < nt; ++t) {
    int rem = nt - t;
    if (rem >= 3)      asm volatile("s_waitcnt vmcnt(4)" ::: "memory");
    else if (rem == 2) asm volatile("s_waitcnt vmcnt(2)" ::: "memory");
    else               asm volatile("s_waitcnt vmcnt(0)" ::: "memory");
    __builtin_amdgcn_s_barrier();
    __builtin_amdgcn_sched_barrier(0);

    const ushort* as = As[t & 3];
    const ushort* bs = Bs[t & 3];
    bf16x8 af[2], bfr[4];
#pragma unroll
    for (int i = 0; i < 2; ++i) {
      int ra = wr + i * 16 + lr;
      af[i] = *reinterpret_cast<const bf16x8*>(as + ra * 32 + ((lg ^ ((ra >> 1) & 3)) << 3));
    }
#pragma unroll
    for (int j = 0; j < 4; ++j) {
      int rb = wc + j * 16 + lr;
      bfr[j] = *reinterpret_cast<const bf16x8*>(bs + rb * 32 + ((lg ^ ((rb >> 1) & 3)) << 3));
    }
    asm volatile("s_waitcnt lgkmcnt(0)" ::: "memory");
    __builtin_amdgcn_sched_barrier(0);

    if (t + 3 < nt) stage((t + 3) & 3, t + 3);

#pragma unroll
    for (int i = 0; i < 2; ++i)
#pragma unroll
      for (int j = 0; j < 4; ++j)
        acc[i][j] = __builtin_amdgcn_mfma_f32_16x16x32_bf16(af[i], bfr[j], acc[i][j], 0, 0, 0);
  }

  const int colunit = (n0 + wc) >> 6;
  if (colunit < 40) {
    const bool isQ = (colunit < 32);
    const float* wn = isQ ? qw : kw;
    float wv[4];
#pragma unroll
    for (int j = 0; j < 4; ++j) wv[j] = wn[j * 16 + lr];
    ushort* dst = isQ ? (Qb + (size_t)colunit * TSEQ * 64)
                      : (Kb + (size_t)(colunit - 32) * TSEQ * 64);
#pragma unroll
    for (int i = 0; i < 2; ++i)
#pragma unroll
      for (int r = 0; r < 4; ++r) {
        int row = m0 + wr + i * 16 + lg * 4 + r;
        float ss = 0.f;
#pragma unroll
        for (int j = 0; j < 4; ++j) { float x = acc[i][j][r]; ss += x * x; }
        ss += __shfl_xor(ss, 1); ss += __shfl_xor(ss, 2);
        ss += __shfl_xor(ss, 4); ss += __shfl_xor(ss, 8);
        float rms = rsqrtf(ss * (1.0f / 64.0f) + 1e-6f);
#pragma unroll
        for (int j = 0; j < 4; ++j) {
          float xh = acc[i][j][r] * rms * wv[j];
          float other = __shfl_xor(xh, 1);
          float4 tb = Tbl[(size_t)row * 32 + j * 8 + (lr >> 1)];
          float c = isQ ? tb.x : tb.z;
          float s = isQ ? tb.y : tb.w;
          float outv = (lr & 1) ? (other * s + xh * c) : (xh * c - other * s);
          dst[(size_t)row * 64 + j * 16 + lr] = f2bf(outv);
        }
      }
  } else {
    const int hv = colunit - 40;
#pragma unroll
    for (int i = 0; i < 2; ++i)
#pragma unroll
      for (int j = 0; j < 4; ++j)
#pragma unroll
        for (int r = 0; r < 4; ++r) {
          int row = m0 + wr + i * 16 + lg * 4 + r;
          Vt[((size_t)hv * 64 + j * 16 + lr) * TSEQ + row] = f2bf(acc[i][j][r]);
        }
  }
}

// ---------------- bf16 GEMM: 64x128 tile, 4 LDS buffers / depth-3 (AO, R13 config) ----------------
__global__ __launch_bounds__(256) void k_gemm64(
    const ushort* __restrict__ A, const ushort* __restrict__ B,
    float* __restrict__ C, int M, int N, int K)
{
  __shared__ ushort As[4][64 * 32];
  __shared__ ushort Bs[4][128 * 32];
  const int m0 = blockIdx.y * 64, n0 = blockIdx.x * 128;
  const int tid = threadIdx.x;
  const int w = tid >> 6, lane = tid & 63, lg = lane >> 4, lr = lane & 15;
  const int wr = (w >> 1) * 32, wc = (w & 1) * 64;

  f32x4 acc[2][4];
#pragma unroll
  for (int i = 0; i < 2; ++i)
#pragma unroll
    for (int j = 0; j < 4; ++j) acc[i][j] = (f32x4){0.f, 0.f, 0.f, 0.f};

  const int nt = K >> 5;

  auto stage = [&](int b, int t) {
    const int k0 = t << 5;
    {
      int ci = tid;
      int row = ci >> 2, c = ci & 3;
      int clog = c ^ ((row >> 1) & 3);
      gload16(A + (size_t)(m0 + row) * K + k0 + clog * 8, As[b] + ci * 8);
    }
#pragma unroll
    for (int j = 0; j < 2; ++j) {
      int ci = j * 256 + tid;
      int row = ci >> 2, c = ci & 3;
      int clog = c ^ ((row >> 1) & 3);
      gload16(B + (size_t)(n0 + row) * K + k0 + clog * 8, Bs[b] + ci * 8);
    }
  };

  stage(0, 0); stage(1, 1); stage(2, 2);

  for (int t = 0; t < nt; ++t) {
    int rem = nt - t;
    if (rem >= 3)      asm volatile("s_waitcnt vmcnt(6)" ::: "memory");
    else if (rem == 2) asm volatile("s_waitcnt vmcnt(3)" ::: "memory");
    else               asm volatile("s_waitcnt vmcnt(0)" ::: "memory");
    __builtin_amdgcn_s_barrier();
    __builtin_amdgcn_sched_barrier(0);

    const ushort* as = As[t & 3];
    const ushort* bs = Bs[t & 3];
    bf16x8 af[2], bfr[4];
#pragma unroll
    for (int i = 0; i < 2; ++i) {
      int ra = wr + i * 16 + lr;
      af[i] = *reinterpret_cast<const bf16x8*>(as + ra * 32 + ((lg ^ ((ra >> 1) & 3)) << 3));
    }
#pragma unroll
    for (int j = 0; j < 4; ++j) {
      int rb = wc + j * 16 + lr;
      bfr[j] = *reinterpret_cast<const bf16x8*>(bs + rb * 32 + ((lg ^ ((rb >> 1) & 3)) << 3));
    }
    asm volatile("s_waitcnt lgkmcnt(0)" ::: "memory");
    __builtin_amdgcn_sched_barrier(0);

    if (t + 3 < nt) stage((t + 3) & 3, t + 3);

#pragma unroll
    for (int i = 0; i < 2; ++i)
#pragma unroll
      for (int j = 0; j < 4; ++j)
        acc[i][j] = __builtin_amdgcn_mfma_f32_16x16x32_bf16(af[i], bfr[j], acc[i][j], 0, 0, 0);
  }

#pragma unroll
  for (int i = 0; i < 2; ++i)
#pragma unroll
    for (int j = 0; j < 4; ++j)
#pragma unroll
      for (int r = 0; r < 4; ++r)
        C[(size_t)(m0 + wr + i * 16 + lg * 4 + r) * N + n0 + wc + j * 16 + lr] = acc[i][j][r];
}

// ---------------- flash attention: R13-proven (128-q block, 8 waves, KVBLK=64, LPT grid) ----------------
// + Wo f32->bf16 conversion absorbed into the idle tail (needed only by the NEXT kernel).
__global__ __launch_bounds__(512) void k_attn(
    const ushort* __restrict__ Qb, const ushort* __restrict__ Kb,
    const ushort* __restrict__ Vt, ushort* __restrict__ AO,
    const float* __restrict__ Wo, ushort* __restrict__ Wob)
{
  __shared__ ushort Ks[2][64 * 64];
  __shared__ ushort Vs[2][64 * 64];

  const int h = blockIdx.x;
  const int q0 = ((int)gridDim.y - 1 - (int)blockIdx.y) * 128;  // heavy blocks first
  const int tid = threadIdx.x;
  const int w = tid >> 6, lane = tid & 63;
  const int lg = lane >> 4, lr = lane & 15;
  const int qrow = q0 + w * 16 + lr;

  const ushort* qp = Qb + ((size_t)h * TSEQ + qrow) * 64;
  const bf16x8 qf0 = *reinterpret_cast<const bf16x8*>(qp + lg * 8);
  const bf16x8 qf1 = *reinterpret_cast<const bf16x8*>(qp + 32 + lg * 8);
  const int hk = h >> 2;
  const char* Kh = (const char*)(Kb + (size_t)hk * TSEQ * 64);
  const char* Vh = (const char*)(Vt + (size_t)hk * 64 * TSEQ);

  float m = -1e30f, lsum = 0.0f;
  f32x4 o[4];
#pragma unroll
  for (int dt = 0; dt < 4; ++dt) o[dt] = (f32x4){0.f, 0.f, 0.f, 0.f};

  const int wlo = (q0 >= 1152) ? (q0 - 1024) : 128;
  int nwin = (q0 + 64 - wlo) / 64 + 1;
  if (nwin < 0) nwin = 0;
  const int ntiles = 2 + nwin;
  const int qw0 = q0 + w * 16;
  const int wmaxstart = ((qw0 + 15 - 1023) > 128) ? (qw0 + 15 - 1023) : 128;
  const int wminstart = ((qw0 - 1023) > 128) ? (qw0 - 1023) : 128;
  const int wstart_lane = ((qrow - 1023) > 128) ? (qrow - 1023) : 128;

  auto stage = [&](int b, int kb) {
    int off = tid * 16;
    int r = off >> 7, bp = off & 127;
    int bs = bp ^ ((r & 7) << 4);
    gload16(Kh + (size_t)(kb + r) * 128 + bs, (char*)Ks[b] + off);
    gload16(Vh + (size_t)r * (TSEQ * 2) + (size_t)kb * 2 + bs, (char*)Vs[b] + off);
  };

  stage(0, 0);

  for (int ti = 0; ti < ntiles; ++ti) {
    const int kb = (ti < 2) ? ti * 64 : wlo + (ti - 2) * 64;
    __syncthreads();
    if (ti + 1 < ntiles) {
      const int kb1 = (ti + 1 < 2) ? (ti + 1) * 64 : wlo + (ti - 1) * 64;
      stage((ti + 1) & 1, kb1);
    }
    if (ti >= 2 && ((kb > qw0 + 15) || (kb + 63 < wminstart))) continue;

    const char* ks = (const char*)Ks[ti & 1];
    const char* vs = (const char*)Vs[ti & 1];
    const bool needmask = (ti >= 2) && !((kb + 63 <= qw0) && (kb >= wmaxstart));

    f32x4 st[4];
#pragma unroll
    for (int s = 0; s < 4; ++s) {
      int row = s * 16 + lr;
      int sw = (row & 7) << 4;
      bf16x8 kf0 = *reinterpret_cast<const bf16x8*>(ks + row * 128 + ((lg * 16) ^ sw));
      bf16x8 kf1 = *reinterpret_cast<const bf16x8*>(ks + row * 128 + ((64 + lg * 16) ^ sw));
      f32x4 acc = (f32x4){0.f, 0.f, 0.f, 0.f};
      acc = __builtin_amdgcn_mfma_f32_16x16x32_bf16(kf0, qf0, acc, 0, 0, 0);
      acc = __builtin_amdgcn_mfma_f32_16x16x32_bf16(kf1, qf1, acc, 0, 0, 0);
      st[s] = acc;
    }
    if (needmask) {
#pragma unroll
      for (int s = 0; s < 4; ++s)
#pragma unroll
        for (int r = 0; r < 4; ++r) {
          int key = kb + s * 16 + lg * 4 + r;
          bool ok = (key >= wstart_lane) && (key <= qrow);
          if (!ok) st[s][r] = -1e30f;
        }
    }
    float pmax = st[0][0];
#pragma unroll
    for (int s = 0; s < 4; ++s)
#pragma unroll
      for (int r = 0; r < 4; ++r) pmax = fmaxf(pmax, st[s][r]);
    pmax = fmaxf(pmax, __shfl_xor(pmax, 16));
    pmax = fmaxf(pmax, __shfl_xor(pmax, 32));

    const bool defer = __all(pmax <= m + 8.0f);
    if (!defer) {
      float mnew = fmaxf(m, pmax);
      float sc = fexp2(m - mnew);
      m = mnew;
      lsum *= sc;
#pragma unroll
      for (int dt = 0; dt < 4; ++dt) o[dt] = o[dt] * sc;
    }

    float psum = 0.f;
    bf16x4 pb[4];
#pragma unroll
    for (int s = 0; s < 4; ++s) {
      float e0 = fexp2(st[s][0] - m);
      float e1 = fexp2(st[s][1] - m);
      float e2 = fexp2(st[s][2] - m);
      float e3 = fexp2(st[s][3] - m);
      psum += (e0 + e1) + (e2 + e3);
      union { uint32_t u[2]; bf16x4 b; } pk;
      pk.u[0] = cvtpk(e0, e1);
      pk.u[1] = cvtpk(e2, e3);
      pb[s] = pk.b;
    }
    psum += __shfl_xor(psum, 16);
    psum += __shfl_xor(psum, 32);
    lsum += psum;

#pragma unroll
    for (int dt = 0; dt < 4; ++dt) {
      int row = dt * 16 + lr;
      int sw = (row & 7) << 4;
#pragma unroll
      for (int s = 0; s < 4; ++s) {
        bf16x4 vf = *reinterpret_cast<const bf16x4*>(vs + row * 128 + ((s * 32 + lg * 8) ^ sw));
        o[dt] = __builtin_amdgcn_mfma_f32_16x16x16bf16_1k(vf, pb[s], o[dt], 0, 0, 0);
      }
    }
  }

  float inv = 1.0f / lsum;
#pragma unroll
  for (int dt = 0; dt < 4; ++dt)
#pragma unroll
    for (int r = 0; r < 4; ++r)
      AO[(size_t)qrow * AON + h * 64 + dt * 16 + lg * 4 + r] = f2bf(o[dt][r] * inv);

  // -------- absorbed Wo f32->bf16 conversion (hides in the LPT idle tail) --------
  {
    int bid = blockIdx.y * gridDim.x + blockIdx.x;           // 512 blocks
    int idx = bid * 512 + tid;                               // 262144 threads
#pragma unroll
    for (int it = 0; it < 4; ++it) {                         // 4 * 262144 = 1048576 float4s
      int i = idx + it * 262144;
      float4 v = reinterpret_cast<const float4*>(Wo)[i];
      ushort4 ov;
      ov.x = f2bf(v.x); ov.y = f2bf(v.y); ov.z = f2bf(v.z); ov.w = f2bf(v.w);
      reinterpret_cast<ushort4*>(Wob)[i] = ov;
    }
  }
}

// ---------------- launch ----------------
extern "C" void kernel_launch(void* const* d_in, const int* in_sizes, int n_in,
                              void* d_out, int out_size, void* d_ws, size_t ws_size,
                              hipStream_t stream) {
  const float* hs = (const float*)d_in[0];
  const int* pos  = (const int*)d_in[1];
  const float* Wq = (const float*)d_in[2];
  const float* Wk = (const float*)d_in[3];
  const float* Wv = (const float*)d_in[4];
  const float* Wo = (const float*)d_in[5];
  const float* qw = (const float*)d_in[6];
  const float* kw = (const float*)d_in[7];
  float* out = (float*)d_out;

  char* ws = (char*)d_ws;
  ushort* Xb    = (ushort*)ws; ws += (size_t)2048 * 2048 * 2;
  ushort* Wqkvb = (ushort*)ws; ws += (size_t)3072 * 2048 * 2;
  ushort* Wob   = (ushort*)ws; ws += (size_t)2048 * 2048 * 2;
  float4* Tbl   = (float4*)ws; ws += (size_t)2048 * 32 * 16;
  ushort* Qb    = (ushort*)ws; ws += (size_t)32 * 2048 * 64 * 2;
  ushort* Kb    = (ushort*)ws; ws += (size_t)8 * 2048 * 64 * 2;
  ushort* Vt    = (ushort*)ws; ws += (size_t)8 * 64 * 2048 * 2;
  ushort* AO    = (ushort*)ws;

  k_cvt_all<<<2048, 256, 0, stream>>>(hs, Wq, Wk, Wv, pos, Xb, Wqkvb, Tbl);

  k_gemm_qkv<<<dim3(QKVN / 128, TSEQ / 128), 512, 0, stream>>>(
      Xb, Wqkvb, qw, kw, Tbl, Qb, Kb, Vt, TSEQ, QKVN, DMODEL);
  k_attn<<<dim3(NHEAD, TSEQ / 128), 512, 0, stream>>>(Qb, Kb, Vt, AO, Wo, Wob);
  k_gemm64<<<dim3(DMODEL / 128, TSEQ / 64), 256, 0, stream>>>(AO, Wob, out, TSEQ, DMODEL, AON);
}